// Round 1
// baseline (6297.121 us; speedup 1.0000x reference)
//
#include <hip/hip_runtime.h>
#include <math.h>

#define N_NODES 20000
#define N_EDGES 320000
#define DIM 256
#define HID 256
#define EDIM 64
#define NLAYERS 4
#define NGRAPH 64

__device__ __forceinline__ float silu_f(float v){ return v / (1.0f + __expf(-v)); }

// ---------------- edge distance ----------------
__global__ void k_dist(const int* __restrict__ ei, const float* __restrict__ pos,
                       float* __restrict__ dist){
  int e = blockIdx.x*256 + threadIdx.x;
  if (e >= N_EDGES) return;
  int s = ei[e];            // src
  int d = ei[N_EDGES + e];  // dst
  float dx = pos[s*3+0]-pos[d*3+0];
  float dy = pos[s*3+1]-pos[d*3+1];
  float dz = pos[s*3+2]-pos[d*3+2];
  dist[e] = sqrtf(dx*dx+dy*dy+dz*dz);
}

// ---------------- generic fp32 tiled GEMM: C[M,N] = A[M,K]@B[K,N] (+bias)(+silu) ----------------
// block: 256 threads, tile 64x64, each thread 4x4. K must be multiple of 16.
template<int BIAS, int ACT>
__global__ __launch_bounds__(256)
void k_gemm(const float* __restrict__ A, const float* __restrict__ B,
            const float* __restrict__ bias, float* __restrict__ C,
            int M, int K, int N){
  __shared__ float As[16][64+1];
  __shared__ float Bs[16][64+1];
  int tx = threadIdx.x & 15, ty = threadIdx.x >> 4;
  int m0 = blockIdx.y*64, n0 = blockIdx.x*64;
  float acc[4][4] = {};
  for (int k0=0;k0<K;k0+=16){
    #pragma unroll
    for (int r=0;r<4;r++){
      int q = threadIdx.x + 256*r;
      int m = q>>4, k = q&15;
      int gm = m0+m;
      As[k][m] = (gm<M)? A[(size_t)gm*K + k0+k] : 0.f;
      int n = q&63, kb = q>>6;
      int gn = n0+n;
      Bs[kb][n] = (gn<N)? B[(size_t)(k0+kb)*N + gn] : 0.f;
    }
    __syncthreads();
    #pragma unroll
    for (int kk=0;kk<16;kk++){
      float a[4], b[4];
      #pragma unroll
      for(int i=0;i<4;i++) a[i]=As[kk][ty*4+i];
      #pragma unroll
      for(int j=0;j<4;j++) b[j]=Bs[kk][tx*4+j];
      #pragma unroll
      for(int i=0;i<4;i++)
        #pragma unroll
        for(int j=0;j<4;j++) acc[i][j] += a[i]*b[j];
    }
    __syncthreads();
  }
  #pragma unroll
  for(int i=0;i<4;i++){
    int gm=m0+ty*4+i;
    if(gm>=M) continue;
    #pragma unroll
    for(int j=0;j<4;j++){
      int gn=n0+tx*4+j;
      if(gn>=N) continue;
      float v=acc[i][j];
      if(BIAS) v += bias[gn];
      if(ACT) v = silu_f(v);
      C[(size_t)gm*N+gn]=v;
    }
  }
}

// ---------------- fold node bias through msg_w1 ----------------
// bias_m[j] = msg_b1[j] + sum_k node_b[k]*(w1[k][j] + w1[256+k][j])
__global__ void k_biasm(const float* __restrict__ nb, const float* __restrict__ w1,
                        const float* __restrict__ mb1, float* __restrict__ bias_m){
  int j = threadIdx.x;
  float s = mb1[j];
  for(int k=0;k<256;k++) s += nb[k]*(w1[k*256+j] + w1[(256+k)*256+j]);
  bias_m[j]=s;
}

// ---------------- fused edge kernel ----------------
// per edge: h = silu(t_a[dst] + t_b[src] + dist*w1c + bias_m)
//           out = silu(h @ w2 + b2) + (edge_attr @ ew + eb)
//           atomicAdd(aggr[dst], out)
__global__ __launch_bounds__(256)
void k_edge(const float* __restrict__ t_a, const float* __restrict__ t_b,
            const float* __restrict__ dist, const int* __restrict__ ei,
            const float* __restrict__ edge_attr,
            const float* __restrict__ w1c, const float* __restrict__ bias_m,
            const float* __restrict__ w2, const float* __restrict__ b2,
            const float* __restrict__ ew, const float* __restrict__ eb,
            float* __restrict__ aggr)
{
  __shared__ float h[16][256];
  __shared__ float ea[16][64];
  __shared__ int sdst[16];
  __shared__ int ssrc[16];
  __shared__ float sdist[16];
  int j = threadIdx.x;
  int e0 = blockIdx.x*16;
  if (j < 16){
    sdst[j] = ei[N_EDGES + e0 + j];
    ssrc[j] = ei[e0 + j];
    sdist[j] = dist[e0 + j];
  }
  #pragma unroll
  for(int r=0;r<4;r++){
    int q = j + 256*r;
    int e = q>>6, k=q&63;
    ea[e][k] = edge_attr[(size_t)(e0+e)*64 + k];
  }
  __syncthreads();
  float wc = w1c[j], bm = bias_m[j];
  #pragma unroll
  for(int e=0;e<16;e++){
    float pre = t_a[(size_t)sdst[e]*256 + j] + t_b[(size_t)ssrc[e]*256 + j]
              + sdist[e]*wc + bm;
    h[e][j] = silu_f(pre);
  }
  __syncthreads();
  float acc[16]={};
  for(int k=0;k<256;k+=4){
    float w0=w2[(k+0)*256+j], w1v=w2[(k+1)*256+j], w2v=w2[(k+2)*256+j], w3v=w2[(k+3)*256+j];
    #pragma unroll
    for(int e=0;e<16;e++){
      float4 hv = *(const float4*)&h[e][k];
      acc[e] += hv.x*w0 + hv.y*w1v + hv.z*w2v + hv.w*w3v;
    }
  }
  float eacc[16]={};
  for(int k=0;k<64;k+=4){
    float w0=ew[(k+0)*256+j], w1v=ew[(k+1)*256+j], w2v=ew[(k+2)*256+j], w3v=ew[(k+3)*256+j];
    #pragma unroll
    for(int e=0;e<16;e++){
      float4 av = *(const float4*)&ea[e][k];
      eacc[e] += av.x*w0 + av.y*w1v + av.z*w2v + av.w*w3v;
    }
  }
  float bb = b2[j], ebj = eb[j];
  #pragma unroll
  for(int e=0;e<16;e++){
    float outv = silu_f(acc[e]+bb) + eacc[e] + ebj;
    atomicAdd(&aggr[(size_t)sdst[e]*256 + j], outv);
  }
}

// ---------------- pooling ----------------
__global__ void k_pool(const float* __restrict__ x, const int* __restrict__ batch,
                       float* __restrict__ pooled){
  int n = blockIdx.x;
  int j = threadIdx.x;
  int g = batch[n];
  atomicAdd(&pooled[g*256+j], x[(size_t)n*256+j]);
}

// ---------------- head ----------------
__global__ void k_head(const float* __restrict__ pooled, const float* __restrict__ fw1,
                       const float* __restrict__ fb1, const float* __restrict__ fw2,
                       const float* __restrict__ fb2, float* __restrict__ out){
  __shared__ float red[256];
  int g = blockIdx.x, j = threadIdx.x;
  float s = fb1[j];
  const float* p = &pooled[g*256];
  for(int k=0;k<256;k++) s += p[k]*fw1[k*256+j];
  float hv = silu_f(s)*fw2[j];
  red[j]=hv; __syncthreads();
  for(int off=128;off>0;off>>=1){ if(j<off) red[j]+=red[j+off]; __syncthreads(); }
  if(j==0) out[g] = red[0] + fb2[0];
}

extern "C" void kernel_launch(void* const* d_in, const int* in_sizes, int n_in,
                              void* d_out, int out_size, void* d_ws, size_t ws_size,
                              hipStream_t stream) {
  const float* x_in      = (const float*)d_in[0];
  const float* edge_attr = (const float*)d_in[1];
  const float* pos       = (const float*)d_in[2];
  const int*   ei        = (const int*)d_in[3];
  const int*   batch     = (const int*)d_in[4];
  const float* node_w    = (const float*)d_in[5];
  const float* node_b    = (const float*)d_in[6];
  const float* edge_w    = (const float*)d_in[7];
  const float* edge_b    = (const float*)d_in[8];
  const float* msg_w1    = (const float*)d_in[9];
  const float* msg_b1    = (const float*)d_in[10];
  const float* msg_w2    = (const float*)d_in[11];
  const float* msg_b2    = (const float*)d_in[12];
  const float* upd_w1    = (const float*)d_in[13];
  const float* upd_b1    = (const float*)d_in[14];
  const float* upd_w2    = (const float*)d_in[15];
  const float* upd_b2    = (const float*)d_in[16];
  const float* fc_w1     = (const float*)d_in[17];
  const float* fc_b1     = (const float*)d_in[18];
  const float* fc_w2     = (const float*)d_in[19];
  const float* fc_b2     = (const float*)d_in[20];
  float* out = (float*)d_out;

  float* ws = (float*)d_ws;
  float* dist  = ws; ws += N_EDGES;
  float* Wa    = ws; ws += 256*256;
  float* Wb    = ws; ws += 256*256;
  float* biasm = ws; ws += 256;
  float* t_a   = ws; ws += (size_t)N_NODES*256;
  float* t_b   = ws; ws += (size_t)N_NODES*256;
  float* aggr  = ws; ws += (size_t)N_NODES*256;
  float* xbuf  = ws; ws += (size_t)N_NODES*256;
  float* pooled= ws; ws += NGRAPH*256;
  float* hupd  = t_a;  // alias: t_a dead after edge kernel

  k_dist<<<(N_EDGES+255)/256, 256, 0, stream>>>(ei, pos, dist);

  for(int l=0;l<NLAYERS;l++){
    const float* nw  = node_w + (size_t)l*256*256;
    const float* nb  = node_b + l*256;
    const float* w1  = msg_w1 + (size_t)l*513*256;
    const float* mb1 = msg_b1 + l*256;
    const float* w2  = msg_w2 + (size_t)l*256*256;
    const float* mb2 = msg_b2 + l*256;
    const float* ewp = edge_w + (size_t)l*64*256;
    const float* ebp = edge_b + l*256;
    const float* uw1 = upd_w1 + (size_t)l*256*256;
    const float* ub1 = upd_b1 + l*256;
    const float* uw2 = upd_w2 + (size_t)l*256*256;
    const float* ub2 = upd_b2 + l*256;
    const float* xcur = (l==0)? x_in : xbuf;

    // fold node_w through msg_w1 halves: Wa = nw@w1[:256], Wb = nw@w1[256:512]
    k_gemm<0,0><<<dim3(4,4), 256, 0, stream>>>(nw, w1,         nullptr, Wa, 256,256,256);
    k_gemm<0,0><<<dim3(4,4), 256, 0, stream>>>(nw, w1+256*256, nullptr, Wb, 256,256,256);
    k_biasm<<<1,256,0,stream>>>(nb, w1, mb1, biasm);

    // node-side terms
    k_gemm<0,0><<<dim3(4,313), 256, 0, stream>>>(xcur, Wa, nullptr, t_a, N_NODES,256,256);
    k_gemm<0,0><<<dim3(4,313), 256, 0, stream>>>(xcur, Wb, nullptr, t_b, N_NODES,256,256);

    hipMemsetAsync(aggr, 0, (size_t)N_NODES*256*sizeof(float), stream);

    k_edge<<<N_EDGES/16, 256, 0, stream>>>(t_a, t_b, dist, ei, edge_attr,
                                           w1 + 512*256, biasm, w2, mb2, ewp, ebp, aggr);

    // update MLP
    k_gemm<1,1><<<dim3(4,313), 256, 0, stream>>>(aggr, uw1, ub1, hupd, N_NODES,256,256);
    k_gemm<1,0><<<dim3(4,313), 256, 0, stream>>>(hupd, uw2, ub2, xbuf, N_NODES,256,256);
  }

  hipMemsetAsync(pooled, 0, NGRAPH*256*sizeof(float), stream);
  k_pool<<<N_NODES, 256, 0, stream>>>(xbuf, batch, pooled);
  k_head<<<NGRAPH, 256, 0, stream>>>(pooled, fc_w1, fc_b1, fc_w2, fc_b2, out);
}

// Round 2
// 2912.091 us; speedup vs baseline: 2.1624x; 2.1624x over previous
//
#include <hip/hip_runtime.h>
#include <hip/hip_bf16.h>
#include <math.h>

#define N_NODES 20000
#define N_EDGES 320000
#define DIM 256
#define HID 256
#define EDIM 64
#define NLAYERS 4
#define NGRAPH 64

typedef __attribute__((ext_vector_type(8))) short short8;
typedef __attribute__((ext_vector_type(4))) float f32x4;

__device__ __forceinline__ float silu_f(float v){ return v / (1.0f + __expf(-v)); }

// ---------------- edge distance ----------------
__global__ void k_dist(const int* __restrict__ ei, const float* __restrict__ pos,
                       float* __restrict__ dist){
  int e = blockIdx.x*256 + threadIdx.x;
  if (e >= N_EDGES) return;
  int s = ei[e];            // src
  int d = ei[N_EDGES + e];  // dst
  float dx = pos[s*3+0]-pos[d*3+0];
  float dy = pos[s*3+1]-pos[d*3+1];
  float dz = pos[s*3+2]-pos[d*3+2];
  dist[e] = sqrtf(dx*dx+dy*dy+dz*dz);
}

// ---------------- EA_aug: per-dst sum of edge_attr (cols 0..63), count (col 64), zeros to 80 ----
__global__ void k_eaagg(const int* __restrict__ ei, const float* __restrict__ edge_attr,
                        float* __restrict__ EA_aug){
  int idx = blockIdx.x*256 + threadIdx.x;   // e*64 + k
  if (idx >= N_EDGES*64) return;
  int e = idx >> 6, k = idx & 63;
  int d = ei[N_EDGES + e];
  atomicAdd(&EA_aug[(size_t)d*80 + k], edge_attr[idx]);
  if (k == 0) atomicAdd(&EA_aug[(size_t)d*80 + 64], 1.0f);
}

// ---------------- generic fp32 tiled GEMM: C[M,N] = A[M,K]@B[K,N] (+bias)(+silu) ----------------
// block: 256 threads, tile 64x64, each thread 4x4. K must be multiple of 16.
template<int BIAS, int ACT, int OBF16>
__global__ __launch_bounds__(256)
void k_gemm(const float* __restrict__ A, const float* __restrict__ B,
            const float* __restrict__ bias, void* __restrict__ Cv,
            int M, int K, int N){
  __shared__ float As[16][64+1];
  __shared__ float Bs[16][64+1];
  int tx = threadIdx.x & 15, ty = threadIdx.x >> 4;
  int m0 = blockIdx.y*64, n0 = blockIdx.x*64;
  float acc[4][4] = {};
  for (int k0=0;k0<K;k0+=16){
    #pragma unroll
    for (int r=0;r<4;r++){
      int q = threadIdx.x + 256*r;
      int m = q>>4, k = q&15;
      int gm = m0+m;
      As[k][m] = (gm<M)? A[(size_t)gm*K + k0+k] : 0.f;
      int n = q&63, kb = q>>6;
      int gn = n0+n;
      Bs[kb][n] = (gn<N)? B[(size_t)(k0+kb)*N + gn] : 0.f;
    }
    __syncthreads();
    #pragma unroll
    for (int kk=0;kk<16;kk++){
      float a[4], b[4];
      #pragma unroll
      for(int i=0;i<4;i++) a[i]=As[kk][ty*4+i];
      #pragma unroll
      for(int j=0;j<4;j++) b[j]=Bs[kk][tx*4+j];
      #pragma unroll
      for(int i=0;i<4;i++)
        #pragma unroll
        for(int j=0;j<4;j++) acc[i][j] += a[i]*b[j];
    }
    __syncthreads();
  }
  #pragma unroll
  for(int i=0;i<4;i++){
    int gm=m0+ty*4+i;
    if(gm>=M) continue;
    #pragma unroll
    for(int j=0;j<4;j++){
      int gn=n0+tx*4+j;
      if(gn>=N) continue;
      float v=acc[i][j];
      if(BIAS) v += bias[gn];
      if(ACT) v = silu_f(v);
      if(OBF16) ((__hip_bfloat16*)Cv)[(size_t)gm*N+gn] = __float2bfloat16(v);
      else      ((float*)Cv)[(size_t)gm*N+gn] = v;
    }
  }
}

// ---------------- fold node bias through msg_w1 ----------------
__global__ void k_biasm(const float* __restrict__ nb, const float* __restrict__ w1,
                        const float* __restrict__ mb1, float* __restrict__ bias_m){
  int j = threadIdx.x;
  float s = mb1[j];
  for(int k=0;k<256;k++) s += nb[k]*(w1[k*256+j] + w1[(256+k)*256+j]);
  bias_m[j]=s;
}

// ---------------- transpose+convert msg_w2 [k][n] fp32 -> w2T [n][k] bf16 ----------------
__global__ void k_w2t(const float* __restrict__ w2, __hip_bfloat16* __restrict__ w2T){
  int n = blockIdx.x, k = threadIdx.x;
  w2T[n*256+k] = __float2bfloat16(w2[k*256+n]);
}

// ---------------- build ew_aug [80][256]: rows 0..63 = ew, row 64 = eb, rest 0 --------
__global__ void k_ewaug(const float* __restrict__ ew, const float* __restrict__ eb,
                        float* __restrict__ ewa){
  int r = blockIdx.x, j = threadIdx.x;
  float v = 0.f;
  if (r < 64) v = ew[r*256+j];
  else if (r == 64) v = eb[j];
  ewa[r*256+j] = v;
}

// ---------------- fused edge kernel (MFMA) ----------------
// 32 edges / block. h = silu(t_a[dst]+t_b[src]+dist*w1c+bias_m) in LDS (bf16, swizzled).
// out = silu(h @ w2 + b2); atomicAdd into aggr[dst].
__global__ __launch_bounds__(256)
void k_edge_mfma(const __hip_bfloat16* __restrict__ t_a, const __hip_bfloat16* __restrict__ t_b,
                 const float* __restrict__ dist, const int* __restrict__ ei,
                 const float* __restrict__ w1c, const float* __restrict__ biasm,
                 const __hip_bfloat16* __restrict__ w2T, const float* __restrict__ b2,
                 float* __restrict__ aggr)
{
  __shared__ __align__(16) __hip_bfloat16 h[32][256];
  __shared__ int sdst[32];
  __shared__ int ssrc[32];
  __shared__ float sdist[32];
  int tid = threadIdx.x;
  int e0 = blockIdx.x*32;
  if (tid < 32){
    sdst[tid] = ei[N_EDGES + e0 + tid];
    ssrc[tid] = ei[e0 + tid];
    sdist[tid] = dist[e0 + tid];
  }
  __syncthreads();
  int j = tid;                       // column 0..255
  float wc = w1c[j], bm = biasm[j];
  #pragma unroll 8
  for(int e=0;e<32;e++){
    int d = sdst[e], s = ssrc[e];
    float pre = __bfloat162float(t_a[(size_t)d*256 + j])
              + __bfloat162float(t_b[(size_t)s*256 + j])
              + sdist[e]*wc + bm;
    h[e][j ^ ((e&7)<<3)] = __float2bfloat16(silu_f(pre));
  }
  __syncthreads();

  int wid = tid >> 6, lane = tid & 63;
  int l15 = lane & 15, lq = lane >> 4;
  int nb = wid*64;
  f32x4 acc[2][4];
  #pragma unroll
  for(int mt=0;mt<2;mt++)
    #pragma unroll
    for(int nt=0;nt<4;nt++) acc[mt][nt] = (f32x4){0.f,0.f,0.f,0.f};

  for(int k0=0;k0<256;k0+=32){
    int kc = k0 + 8*lq;
    short8 a[2], b[4];
    #pragma unroll
    for(int mt=0;mt<2;mt++){
      int row = mt*16 + l15;
      a[mt] = *(const short8*)&h[row][kc ^ ((row&7)<<3)];
    }
    #pragma unroll
    for(int nt=0;nt<4;nt++){
      int col = nb + nt*16 + l15;
      b[nt] = *(const short8*)&w2T[(size_t)col*256 + kc];
    }
    #pragma unroll
    for(int mt=0;mt<2;mt++)
      #pragma unroll
      for(int nt=0;nt<4;nt++)
        acc[mt][nt] = __builtin_amdgcn_mfma_f32_16x16x32_bf16(a[mt], b[nt], acc[mt][nt], 0, 0, 0);
  }

  #pragma unroll
  for(int mt=0;mt<2;mt++){
    #pragma unroll
    for(int nt=0;nt<4;nt++){
      int col = nb + nt*16 + l15;
      float bb = b2[col];
      #pragma unroll
      for(int r=0;r<4;r++){
        int row = mt*16 + lq*4 + r;   // edge within block
        float v = silu_f(acc[mt][nt][r] + bb);
        atomicAdd(&aggr[(size_t)sdst[row]*256 + col], v);
      }
    }
  }
}

// ---------------- pooling ----------------
__global__ void k_pool(const float* __restrict__ x, const int* __restrict__ batch,
                       float* __restrict__ pooled){
  int n = blockIdx.x;
  int j = threadIdx.x;
  int g = batch[n];
  atomicAdd(&pooled[g*256+j], x[(size_t)n*256+j]);
}

// ---------------- head ----------------
__global__ void k_head(const float* __restrict__ pooled, const float* __restrict__ fw1,
                       const float* __restrict__ fb1, const float* __restrict__ fw2,
                       const float* __restrict__ fb2, float* __restrict__ out){
  __shared__ float red[256];
  int g = blockIdx.x, j = threadIdx.x;
  float s = fb1[j];
  const float* p = &pooled[g*256];
  for(int k=0;k<256;k++) s += p[k]*fw1[k*256+j];
  float hv = silu_f(s)*fw2[j];
  red[j]=hv; __syncthreads();
  for(int off=128;off>0;off>>=1){ if(j<off) red[j]+=red[j+off]; __syncthreads(); }
  if(j==0) out[g] = red[0] + fb2[0];
}

extern "C" void kernel_launch(void* const* d_in, const int* in_sizes, int n_in,
                              void* d_out, int out_size, void* d_ws, size_t ws_size,
                              hipStream_t stream) {
  const float* x_in      = (const float*)d_in[0];
  const float* edge_attr = (const float*)d_in[1];
  const float* pos       = (const float*)d_in[2];
  const int*   ei        = (const int*)d_in[3];
  const int*   batch     = (const int*)d_in[4];
  const float* node_w    = (const float*)d_in[5];
  const float* node_b    = (const float*)d_in[6];
  const float* edge_w    = (const float*)d_in[7];
  const float* edge_b    = (const float*)d_in[8];
  const float* msg_w1    = (const float*)d_in[9];
  const float* msg_b1    = (const float*)d_in[10];
  const float* msg_w2    = (const float*)d_in[11];
  const float* msg_b2    = (const float*)d_in[12];
  const float* upd_w1    = (const float*)d_in[13];
  const float* upd_b1    = (const float*)d_in[14];
  const float* upd_w2    = (const float*)d_in[15];
  const float* upd_b2    = (const float*)d_in[16];
  const float* fc_w1     = (const float*)d_in[17];
  const float* fc_b1     = (const float*)d_in[18];
  const float* fc_w2     = (const float*)d_in[19];
  const float* fc_b2     = (const float*)d_in[20];
  float* out = (float*)d_out;

  float* ws = (float*)d_ws;
  float* dist   = ws; ws += N_EDGES;
  float* Wa     = ws; ws += 256*256;
  float* Wb     = ws; ws += 256*256;
  float* biasm  = ws; ws += 256;
  float* ew_aug = ws; ws += 80*256;
  float* EA_aug = ws; ws += (size_t)N_NODES*80;
  float* w2T_f  = ws; ws += 256*256/2;          // bf16 [256][256]
  float* t_a_f  = ws; ws += (size_t)N_NODES*128; // bf16 [N][256]
  float* t_b_f  = ws; ws += (size_t)N_NODES*128; // bf16 [N][256]
  float* aggr   = ws; ws += (size_t)N_NODES*256;
  float* xbuf   = ws; ws += (size_t)N_NODES*256;
  float* pooled = ws; ws += NGRAPH*256;
  __hip_bfloat16* t_a = (__hip_bfloat16*)t_a_f;
  __hip_bfloat16* t_b = (__hip_bfloat16*)t_b_f;
  __hip_bfloat16* w2T = (__hip_bfloat16*)w2T_f;
  float* hupd = t_a_f;   // alias: t_a/t_b region (N*256 floats total) dead after edge kernel

  k_dist<<<(N_EDGES+255)/256, 256, 0, stream>>>(ei, pos, dist);

  // one-time per call: per-dst edge_attr sums + counts
  hipMemsetAsync(EA_aug, 0, (size_t)N_NODES*80*sizeof(float), stream);
  k_eaagg<<<(N_EDGES*64+255)/256, 256, 0, stream>>>(ei, edge_attr, EA_aug);

  for(int l=0;l<NLAYERS;l++){
    const float* nw  = node_w + (size_t)l*256*256;
    const float* nb  = node_b + l*256;
    const float* w1  = msg_w1 + (size_t)l*513*256;
    const float* mb1 = msg_b1 + l*256;
    const float* w2  = msg_w2 + (size_t)l*256*256;
    const float* mb2 = msg_b2 + l*256;
    const float* ewp = edge_w + (size_t)l*64*256;
    const float* ebp = edge_b + l*256;
    const float* uw1 = upd_w1 + (size_t)l*256*256;
    const float* ub1 = upd_b1 + l*256;
    const float* uw2 = upd_w2 + (size_t)l*256*256;
    const float* ub2 = upd_b2 + l*256;
    const float* xcur = (l==0)? x_in : xbuf;

    // fold node_w through msg_w1 halves: Wa = nw@w1[:256], Wb = nw@w1[256:512]
    k_gemm<0,0,0><<<dim3(4,4), 256, 0, stream>>>(nw, w1,         nullptr, Wa, 256,256,256);
    k_gemm<0,0,0><<<dim3(4,4), 256, 0, stream>>>(nw, w1+256*256, nullptr, Wb, 256,256,256);
    k_biasm<<<1,256,0,stream>>>(nb, w1, mb1, biasm);
    k_w2t<<<256,256,0,stream>>>(w2, w2T);
    k_ewaug<<<80,256,0,stream>>>(ewp, ebp, ew_aug);

    // node-side terms (bf16 out)
    k_gemm<0,0,1><<<dim3(4,313), 256, 0, stream>>>(xcur, Wa, nullptr, t_a, N_NODES,256,256);
    k_gemm<0,0,1><<<dim3(4,313), 256, 0, stream>>>(xcur, Wb, nullptr, t_b, N_NODES,256,256);

    // aggr initialized with folded edge-embedding segment-sum: EA_aug @ ew_aug
    k_gemm<0,0,0><<<dim3(4,313), 256, 0, stream>>>(EA_aug, ew_aug, nullptr, aggr, N_NODES,80,256);

    k_edge_mfma<<<N_EDGES/32, 256, 0, stream>>>(t_a, t_b, dist, ei,
                                                w1 + 512*256, biasm, w2T, mb2, aggr);

    // update MLP
    k_gemm<1,1,0><<<dim3(4,313), 256, 0, stream>>>(aggr, uw1, ub1, hupd, N_NODES,256,256);
    k_gemm<1,0,0><<<dim3(4,313), 256, 0, stream>>>(hupd, uw2, ub2, xbuf, N_NODES,256,256);
  }

  hipMemsetAsync(pooled, 0, NGRAPH*256*sizeof(float), stream);
  k_pool<<<N_NODES, 256, 0, stream>>>(xbuf, batch, pooled);
  k_head<<<NGRAPH, 256, 0, stream>>>(pooled, fc_w1, fc_b1, fc_w2, fc_b2, out);
}

// Round 4
// 1649.539 us; speedup vs baseline: 3.8175x; 1.7654x over previous
//
#include <hip/hip_runtime.h>
#include <hip/hip_bf16.h>
#include <math.h>

#define N_NODES 20000
#define N_EDGES 320000
#define NGRAPH 64

typedef __attribute__((ext_vector_type(8))) short short8;
typedef __attribute__((ext_vector_type(4))) short short4x;
typedef __attribute__((ext_vector_type(4))) float f32x4;

__device__ __forceinline__ float silu_f(float v){ return v / (1.0f + __expf(-v)); }
__device__ __forceinline__ float bf2f(short s){
  unsigned u = ((unsigned)(unsigned short)s) << 16;
  float f; __builtin_memcpy(&f, &u, 4); return f;
}
__device__ __forceinline__ short f2bf(float f){
  unsigned u; __builtin_memcpy(&u, &f, 4);
  unsigned r = (u + 0x7FFFu + ((u >> 16) & 1u)) >> 16;
  return (short)r;
}

// ---------------- edge distance ----------------
__global__ void k_dist(const int* __restrict__ ei, const float* __restrict__ pos,
                       float* __restrict__ dist){
  int e = blockIdx.x*256 + threadIdx.x;
  if (e >= N_EDGES) return;
  int s = ei[e];
  int d = ei[N_EDGES + e];
  float dx = pos[s*3+0]-pos[d*3+0];
  float dy = pos[s*3+1]-pos[d*3+1];
  float dz = pos[s*3+2]-pos[d*3+2];
  dist[e] = sqrtf(dx*dx+dy*dy+dz*dz);
}

// ---------------- fp32 -> bf16 convert ----------------
__global__ void k_f2b(const float* __restrict__ S, short* __restrict__ D, int n4){
  int i = blockIdx.x*256 + threadIdx.x;
  if (i >= n4) return;
  float4 v = ((const float4*)S)[i];
  short4x o;
  o[0]=f2bf(v.x); o[1]=f2bf(v.y); o[2]=f2bf(v.z); o[3]=f2bf(v.w);
  ((short4x*)D)[i] = o;
}

// ---------------- EA_aug: per-dst sum of edge_attr (cols 0..63), count (col 64), stride 96 ----
__global__ void k_eaagg(const int* __restrict__ ei, const float* __restrict__ edge_attr,
                        float* __restrict__ EA_aug){
  int idx = blockIdx.x*256 + threadIdx.x;   // e*64 + k
  if (idx >= N_EDGES*64) return;
  int e = idx >> 6, k = idx & 63;
  int d = ei[N_EDGES + e];
  atomicAdd(&EA_aug[(size_t)d*96 + k], edge_attr[idx]);
  if (k == 0) atomicAdd(&EA_aug[(size_t)d*96 + 64], 1.0f);
}

// ---------------- 5 weight transposes fp32[256][256] -> bf16 [n][k] ----------------
__global__ void k_trans5(const float* __restrict__ w1, const float* __restrict__ w2,
                         const float* __restrict__ uw1, const float* __restrict__ uw2,
                         short* __restrict__ w1aT, short* __restrict__ w1bT,
                         short* __restrict__ w2T, short* __restrict__ uw1T,
                         short* __restrict__ uw2T){
  const float* S; short* D;
  switch(blockIdx.z){
    case 0: S=w1;          D=w1aT; break;
    case 1: S=w1+256*256;  D=w1bT; break;
    case 2: S=w2;          D=w2T;  break;
    case 3: S=uw1;         D=uw1T; break;
    default: S=uw2;        D=uw2T; break;
  }
  __shared__ float t[32][33];
  int bx = blockIdx.x*32, by = blockIdx.y*32;   // bx: n-block, by: k-block
  int lx = threadIdx.x & 31, ly = threadIdx.x >> 5;
  #pragma unroll
  for(int r=0;r<4;r++){ int k = ly + r*8; t[k][lx] = S[(size_t)(by+k)*256 + bx+lx]; }
  __syncthreads();
  #pragma unroll
  for(int r=0;r<4;r++){
    int n = ly + r*8;
    D[(size_t)(bx+n)*256 + by+lx] = f2bf(t[lx][n]);
  }
}

// ---------------- ew_augT [n=256][c=96] bf16: c<64: ew[c][n]; c==64: eb[n]; else 0 ----
__global__ void k_ewaugT(const float* __restrict__ ew, const float* __restrict__ eb,
                         short* __restrict__ ewT){
  int n = blockIdx.x, c = threadIdx.x;   // block 96 threads
  float v = (c < 64) ? ew[(size_t)c*256 + n] : (c == 64 ? eb[n] : 0.f);
  ewT[(size_t)n*96 + c] = f2bf(v);
}

// ---------------- biasm accumulation (biasm pre-zeroed) ----------------
__global__ void k_biasm_acc(const float* __restrict__ nb, const float* __restrict__ w1,
                            const float* __restrict__ mb1, float* __restrict__ biasm){
  int j = threadIdx.x;
  int b = blockIdx.x;
  if (b == 16){ atomicAdd(&biasm[j], mb1[j]); return; }
  float s = 0.f;
  for(int k = b*16; k < b*16+16; k++)
    s += nb[k]*(w1[(size_t)k*256+j] + w1[(size_t)(256+k)*256+j]);
  atomicAdd(&biasm[j], s);
}

// ---------------- bf16 MFMA GEMM: C[M,Nld] = A[M,K] @ BT[N,K]^T (+bias)(+silu) ------
// 32 rows x 256 cols per block; grid (Ntot/256, M/32); M must be multiple of 32.
template<int K_REAL, int K_LDS, int BIAS, int ACT, int OF32, int OBF16>
__global__ __launch_bounds__(256)
void k_gemm_mfma(const short* __restrict__ A, const short* __restrict__ BT,
                 const float* __restrict__ bias, float* __restrict__ Cf,
                 short* __restrict__ Cb, int M, int Nld){
  __shared__ __align__(16) short As[32][K_LDS];
  const int CHL = K_LDS/8, CH = K_REAL/8;
  int tid = threadIdx.x;
  int m0 = blockIdx.y*32, n0 = blockIdx.x*256;
  for(int c = tid; c < 32*CHL; c += 256){
    int row = c / CHL, ch = c % CHL;
    short8 v;
    if (ch < CH) {
      v = *(const short8*)&A[(size_t)(m0+row)*K_REAL + ch*8];
    } else {
      v = (short8){0,0,0,0,0,0,0,0};
    }
    *(short8*)&As[row][(ch ^ (row&7))*8] = v;
  }
  __syncthreads();
  int wid = tid>>6, lane = tid&63, l15 = lane&15, lq = lane>>4;
  int ncol0 = n0 + wid*64;
  f32x4 acc[2][4];
  #pragma unroll
  for(int mt=0;mt<2;mt++)
    #pragma unroll
    for(int nt=0;nt<4;nt++) acc[mt][nt] = (f32x4){0.f,0.f,0.f,0.f};
  for(int k0=0;k0<K_REAL;k0+=32){
    int kc = k0 + 8*lq;
    short8 a[2], b[4];
    #pragma unroll
    for(int mt=0;mt<2;mt++){
      int row = mt*16 + l15;
      a[mt] = *(const short8*)&As[row][kc ^ ((row&7)<<3)];
    }
    #pragma unroll
    for(int nt=0;nt<4;nt++){
      int col = ncol0 + nt*16 + l15;
      b[nt] = *(const short8*)&BT[(size_t)col*K_REAL + kc];
    }
    #pragma unroll
    for(int mt=0;mt<2;mt++)
      #pragma unroll
      for(int nt=0;nt<4;nt++)
        acc[mt][nt] = __builtin_amdgcn_mfma_f32_16x16x32_bf16(a[mt], b[nt], acc[mt][nt], 0, 0, 0);
  }
  #pragma unroll
  for(int mt=0;mt<2;mt++){
    #pragma unroll
    for(int nt=0;nt<4;nt++){
      int col = ncol0 + nt*16 + l15;
      float bb = BIAS ? bias[col] : 0.f;
      #pragma unroll
      for(int r=0;r<4;r++){
        int row = m0 + mt*16 + lq*4 + r;
        float v = acc[mt][nt][r] + bb;
        if (ACT) v = silu_f(v);
        if (OF32)  Cf[(size_t)row*Nld + col] = v;
        if (OBF16) Cb[(size_t)row*Nld + col] = f2bf(v);
      }
    }
  }
}

// ---------------- fused edge kernel (MFMA) ----------------
// 32 edges/block. h = silu(t_ab[dst][j] + t_ab[src][256+j] + dist*w1c + biasm) in LDS
// (bf16, XOR-swizzled). out = silu(h @ w2 + b2); atomicAdd into aggr[dst].
__global__ __launch_bounds__(256)
void k_edge_mfma(const short* __restrict__ t_ab,
                 const float* __restrict__ dist, const int* __restrict__ ei,
                 const float* __restrict__ w1c, const float* __restrict__ biasm,
                 const short* __restrict__ w2T, const float* __restrict__ b2,
                 float* __restrict__ aggr)
{
  __shared__ __align__(16) short h[32][256];
  __shared__ int sdst[32], ssrc[32];
  __shared__ float sdist[32];
  int tid = threadIdx.x;
  int e0 = blockIdx.x*32;
  if (tid < 32){
    sdst[tid] = ei[N_EDGES + e0 + tid];
    ssrc[tid] = ei[e0 + tid];
    sdist[tid] = dist[e0 + tid];
  }
  __syncthreads();
  int wid = tid>>6, lane = tid&63;
  int half = lane>>5, cl = lane&31;          // 16B chunk: cols 8cl..8cl+7
  float wc8[8], bm8[8];
  {
    float4 w0 = *(const float4*)&w1c[8*cl], w1v = *(const float4*)&w1c[8*cl+4];
    float4 b0 = *(const float4*)&biasm[8*cl], b1v = *(const float4*)&biasm[8*cl+4];
    wc8[0]=w0.x; wc8[1]=w0.y; wc8[2]=w0.z; wc8[3]=w0.w;
    wc8[4]=w1v.x; wc8[5]=w1v.y; wc8[6]=w1v.z; wc8[7]=w1v.w;
    bm8[0]=b0.x; bm8[1]=b0.y; bm8[2]=b0.z; bm8[3]=b0.w;
    bm8[4]=b1v.x; bm8[5]=b1v.y; bm8[6]=b1v.z; bm8[7]=b1v.w;
  }
  #pragma unroll
  for(int p=0;p<4;p++){
    int e = wid*8 + p*2 + half;
    int d = sdst[e], s = ssrc[e];
    float de = sdist[e];
    short8 va = *(const short8*)&t_ab[(size_t)d*512 + 8*cl];
    short8 vb = *(const short8*)&t_ab[(size_t)s*512 + 256 + 8*cl];
    short8 hv;
    #pragma unroll
    for(int i=0;i<8;i++){
      float f = bf2f(va[i]) + bf2f(vb[i]) + de*wc8[i] + bm8[i];
      hv[i] = f2bf(silu_f(f));
    }
    *(short8*)&h[e][(8*cl) ^ ((e&7)<<3)] = hv;
  }
  __syncthreads();

  int l15 = lane & 15, lq = lane >> 4;
  int nb = wid*64;
  f32x4 acc[2][4];
  #pragma unroll
  for(int mt=0;mt<2;mt++)
    #pragma unroll
    for(int nt=0;nt<4;nt++) acc[mt][nt] = (f32x4){0.f,0.f,0.f,0.f};

  for(int k0=0;k0<256;k0+=32){
    int kc = k0 + 8*lq;
    short8 a[2], b[4];
    #pragma unroll
    for(int mt=0;mt<2;mt++){
      int row = mt*16 + l15;
      a[mt] = *(const short8*)&h[row][kc ^ ((row&7)<<3)];
    }
    #pragma unroll
    for(int nt=0;nt<4;nt++){
      int col = nb + nt*16 + l15;
      b[nt] = *(const short8*)&w2T[(size_t)col*256 + kc];
    }
    #pragma unroll
    for(int mt=0;mt<2;mt++)
      #pragma unroll
      for(int nt=0;nt<4;nt++)
        acc[mt][nt] = __builtin_amdgcn_mfma_f32_16x16x32_bf16(a[mt], b[nt], acc[mt][nt], 0, 0, 0);
  }

  #pragma unroll
  for(int mt=0;mt<2;mt++){
    #pragma unroll
    for(int nt=0;nt<4;nt++){
      int col = nb + nt*16 + l15;
      float bb = b2[col];
      #pragma unroll
      for(int r=0;r<4;r++){
        int row = mt*16 + lq*4 + r;   // edge within block
        float v = silu_f(acc[mt][nt][r] + bb);
        atomicAdd(&aggr[(size_t)sdst[row]*256 + col], v);
      }
    }
  }
}

// ---------------- pooling ----------------
__global__ void k_pool(const float* __restrict__ x, const int* __restrict__ batch,
                       float* __restrict__ pooled){
  int n = blockIdx.x;
  int j = threadIdx.x;
  int g = batch[n];
  atomicAdd(&pooled[g*256+j], x[(size_t)n*256+j]);
}

// ---------------- head ----------------
__global__ void k_head(const float* __restrict__ pooled, const float* __restrict__ fw1,
                       const float* __restrict__ fb1, const float* __restrict__ fw2,
                       const float* __restrict__ fb2, float* __restrict__ out){
  __shared__ float red[256];
  int g = blockIdx.x, j = threadIdx.x;
  float s = fb1[j];
  const float* p = &pooled[g*256];
  for(int k=0;k<256;k++) s += p[k]*fw1[k*256+j];
  float hv = silu_f(s)*fw2[j];
  red[j]=hv; __syncthreads();
  for(int off=128;off>0;off>>=1){ if(j<off) red[j]+=red[j+off]; __syncthreads(); }
  if(j==0) out[g] = red[0] + fb2[0];
}

extern "C" void kernel_launch(void* const* d_in, const int* in_sizes, int n_in,
                              void* d_out, int out_size, void* d_ws, size_t ws_size,
                              hipStream_t stream) {
  const float* x_in      = (const float*)d_in[0];
  const float* edge_attr = (const float*)d_in[1];
  const float* pos       = (const float*)d_in[2];
  const int*   ei        = (const int*)d_in[3];
  const int*   batch     = (const int*)d_in[4];
  const float* node_w    = (const float*)d_in[5];
  const float* node_b    = (const float*)d_in[6];
  const float* edge_w    = (const float*)d_in[7];
  const float* edge_b    = (const float*)d_in[8];
  const float* msg_w1    = (const float*)d_in[9];
  const float* msg_b1    = (const float*)d_in[10];
  const float* msg_w2    = (const float*)d_in[11];
  const float* msg_b2    = (const float*)d_in[12];
  const float* upd_w1    = (const float*)d_in[13];
  const float* upd_b1    = (const float*)d_in[14];
  const float* upd_w2    = (const float*)d_in[15];
  const float* upd_b2    = (const float*)d_in[16];
  const float* fc_w1     = (const float*)d_in[17];
  const float* fc_b1     = (const float*)d_in[18];
  const float* fc_w2     = (const float*)d_in[19];
  const float* fc_b2     = (const float*)d_in[20];
  float* out = (float*)d_out;

  float* ws = (float*)d_ws;
  float* dist   = ws; ws += N_EDGES;
  short* x_bf   = (short*)ws; ws += (size_t)N_NODES*256/2;
  short* EA_bf  = (short*)ws; ws += (size_t)N_NODES*96/2;
  short* WabT   = (short*)ws; ws += 512*256/2;
  short* w1aT   = (short*)ws; ws += 256*256/2;
  short* w1bT   = (short*)ws; ws += 256*256/2;
  short* w2T    = (short*)ws; ws += 256*256/2;
  short* uw1T   = (short*)ws; ws += 256*256/2;
  short* uw2T   = (short*)ws; ws += 256*256/2;
  short* ewT    = (short*)ws; ws += 256*96/2;
  short* nw_bf  = (short*)ws; ws += 256*256/2;
  float* biasm  = ws; ws += 256;
  float* tabreg = ws; ws += (size_t)N_NODES*512/2;   // t_ab bf16 / EA_aug fp32 / aggr_bf+h_bf
  float* aggr   = ws; ws += (size_t)N_NODES*256;
  float* pooled = ws; ws += NGRAPH*256;

  short* t_ab    = (short*)tabreg;
  float* EA_aug  = tabreg;
  short* aggr_bf = (short*)tabreg;
  short* h_bf    = (short*)tabreg + (size_t)N_NODES*256;
  float* xfinal  = aggr;   // last layer fp32 output reuses aggr

  k_dist<<<(N_EDGES+255)/256, 256, 0, stream>>>(ei, pos, dist);
  k_f2b<<<(N_NODES*256/4+255)/256, 256, 0, stream>>>(x_in, x_bf, N_NODES*256/4);

  // one-time: per-dst edge_attr sums + counts (stride 96), then bf16
  hipMemsetAsync(EA_aug, 0, (size_t)N_NODES*96*sizeof(float), stream);
  k_eaagg<<<(N_EDGES*64+255)/256, 256, 0, stream>>>(ei, edge_attr, EA_aug);
  k_f2b<<<(N_NODES*96/4+255)/256, 256, 0, stream>>>(EA_aug, EA_bf, N_NODES*96/4);

  for(int l=0;l<4;l++){
    const float* nw  = node_w + (size_t)l*256*256;
    const float* nb  = node_b + l*256;
    const float* w1  = msg_w1 + (size_t)l*513*256;
    const float* mb1 = msg_b1 + l*256;
    const float* w2  = msg_w2 + (size_t)l*256*256;
    const float* mb2 = msg_b2 + l*256;
    const float* ewp = edge_w + (size_t)l*64*256;
    const float* ebp = edge_b + l*256;
    const float* uw1 = upd_w1 + (size_t)l*256*256;
    const float* ub1 = upd_b1 + l*256;
    const float* uw2 = upd_w2 + (size_t)l*256*256;
    const float* ub2 = upd_b2 + l*256;

    // weight prep
    k_trans5<<<dim3(8,8,5), 256, 0, stream>>>(w1, w2, uw1, uw2, w1aT, w1bT, w2T, uw1T, uw2T);
    k_ewaugT<<<256, 96, 0, stream>>>(ewp, ebp, ewT);
    k_f2b<<<64, 256, 0, stream>>>(nw, nw_bf, 256*256/4);
    // WabT[n][k] = (nw @ w1a)^T : A=w1aT, BT=nw_bf
    k_gemm_mfma<256,256,0,0,0,1><<<dim3(1,8), 256, 0, stream>>>(w1aT, nw_bf, nullptr, nullptr, WabT,           256, 256);
    k_gemm_mfma<256,256,0,0,0,1><<<dim3(1,8), 256, 0, stream>>>(w1bT, nw_bf, nullptr, nullptr, WabT+256*256,   256, 256);
    hipMemsetAsync(biasm, 0, 256*sizeof(float), stream);
    k_biasm_acc<<<17, 256, 0, stream>>>(nb, w1, mb1, biasm);

    // t_ab[N][512] = x @ [Wa|Wb]
    k_gemm_mfma<256,256,0,0,0,1><<<dim3(2,625), 256, 0, stream>>>(x_bf, WabT, nullptr, nullptr, t_ab, N_NODES, 512);

    // aggr = EA_bf @ ew_augT (folded edge-embedding segment-sum)
    k_gemm_mfma<96,128,0,0,1,0><<<dim3(1,625), 256, 0, stream>>>(EA_bf, ewT, nullptr, aggr, nullptr, N_NODES, 256);

    k_edge_mfma<<<N_EDGES/32, 256, 0, stream>>>(t_ab, dist, ei, w1 + 512*256, biasm, w2T, mb2, aggr);

    // update MLP
    k_f2b<<<(N_NODES*256/4+255)/256, 256, 0, stream>>>(aggr, aggr_bf, N_NODES*256/4);
    k_gemm_mfma<256,256,1,1,0,1><<<dim3(1,625), 256, 0, stream>>>(aggr_bf, uw1T, ub1, nullptr, h_bf, N_NODES, 256);
    if (l < 3)
      k_gemm_mfma<256,256,1,0,0,1><<<dim3(1,625), 256, 0, stream>>>(h_bf, uw2T, ub2, nullptr, x_bf, N_NODES, 256);
    else
      k_gemm_mfma<256,256,1,0,1,0><<<dim3(1,625), 256, 0, stream>>>(h_bf, uw2T, ub2, xfinal, nullptr, N_NODES, 256);
  }

  hipMemsetAsync(pooled, 0, NGRAPH*256*sizeof(float), stream);
  k_pool<<<N_NODES, 256, 0, stream>>>(xfinal, batch, pooled);
  k_head<<<NGRAPH, 256, 0, stream>>>(pooled, fc_w1, fc_b1, fc_w2, fc_b2, out);
}

// Round 5
// 1381.354 us; speedup vs baseline: 4.5587x; 1.1941x over previous
//
#include <hip/hip_runtime.h>
#include <hip/hip_bf16.h>
#include <math.h>

#define N_NODES 20000
#define N_EDGES 320000
#define NGRAPH 64

typedef __attribute__((ext_vector_type(8))) short short8;
typedef __attribute__((ext_vector_type(4))) short short4x;
typedef __attribute__((ext_vector_type(4))) float f32x4;

__device__ __forceinline__ float silu_f(float v){ return v / (1.0f + __expf(-v)); }
__device__ __forceinline__ float bf2f(short s){
  unsigned u = ((unsigned)(unsigned short)s) << 16;
  float f; __builtin_memcpy(&f, &u, 4); return f;
}
__device__ __forceinline__ short f2bf(float f){
  unsigned u; __builtin_memcpy(&u, &f, 4);
  unsigned r = (u + 0x7FFFu + ((u >> 16) & 1u)) >> 16;
  return (short)r;
}

// ---------------- CSR build: histogram, scan, scatter ----------------
__global__ void k_hist(const int* __restrict__ ei, int* __restrict__ cnt){
  int e = blockIdx.x*256 + threadIdx.x;
  if (e >= N_EDGES) return;
  atomicAdd(&cnt[ei[N_EDGES + e]], 1);
}

__global__ void k_scan(const int* __restrict__ cnt, int* __restrict__ row_ptr,
                       int* __restrict__ off){
  __shared__ int ssum[256];
  int t = threadIdx.x;
  const int CHK = (N_NODES + 255)/256;   // 79
  int base = t*CHK;
  int s = 0;
  for(int i=0;i<CHK;i++){ int idx=base+i; if(idx<N_NODES) s += cnt[idx]; }
  ssum[t]=s; __syncthreads();
  for(int o=1;o<256;o<<=1){
    int v = (t>=o)? ssum[t-o] : 0;
    __syncthreads();
    ssum[t] += v;
    __syncthreads();
  }
  int pre = (t==0)? 0 : ssum[t-1];
  for(int i=0;i<CHK;i++){
    int idx=base+i; if(idx>=N_NODES) break;
    row_ptr[idx]=pre; off[idx]=pre; pre += cnt[idx];
  }
  if(t==255) row_ptr[N_NODES]=pre;
}

__global__ void k_scatter(const int* __restrict__ ei, int* __restrict__ off,
                          int* __restrict__ src_s, int* __restrict__ dst_s,
                          int* __restrict__ eid_s){
  int e = blockIdx.x*256 + threadIdx.x;
  if (e >= N_EDGES) return;
  int d = ei[N_EDGES + e];
  int p = atomicAdd(&off[d], 1);
  dst_s[p]=d; src_s[p]=ei[e]; eid_s[p]=e;
}

// ---------------- edge distance (sorted order) ----------------
__global__ void k_dist_s(const int* __restrict__ src_s, const int* __restrict__ dst_s,
                         const float* __restrict__ pos, float* __restrict__ dist_s){
  int i = blockIdx.x*256 + threadIdx.x;
  if (i >= N_EDGES) return;
  int s = src_s[i], d = dst_s[i];
  float dx = pos[s*3+0]-pos[d*3+0];
  float dy = pos[s*3+1]-pos[d*3+1];
  float dz = pos[s*3+2]-pos[d*3+2];
  dist_s[i] = sqrtf(dx*dx+dy*dy+dz*dz);
}

// ---------------- EA_aug via CSR: per-dst sum of edge_attr, count, zeros (stride 96) ----
__global__ void k_eaagg_s(const int* __restrict__ row_ptr, const int* __restrict__ eid_s,
                          const float* __restrict__ edge_attr, float* __restrict__ EA){
  int sub = threadIdx.x>>6, j = threadIdx.x&63;
  int d = blockIdx.x*4 + sub;
  if (d >= N_NODES) return;
  int b = row_ptr[d], e = row_ptr[d+1];
  float s = 0.f;
  for(int i=b;i<e;i++) s += edge_attr[(size_t)eid_s[i]*64 + j];
  EA[(size_t)d*96 + j] = s;
  if (j < 32) EA[(size_t)d*96 + 64 + j] = (j==0) ? (float)(e-b) : 0.f;
}

// ---------------- fp32 -> bf16 convert ----------------
__global__ void k_f2b(const float* __restrict__ S, short* __restrict__ D, int n4){
  int i = blockIdx.x*256 + threadIdx.x;
  if (i >= n4) return;
  float4 v = ((const float4*)S)[i];
  short4x o;
  o[0]=f2bf(v.x); o[1]=f2bf(v.y); o[2]=f2bf(v.z); o[3]=f2bf(v.w);
  ((short4x*)D)[i] = o;
}

// ---------------- 5 weight transposes fp32[256][256] -> bf16 [n][k] ----------------
__global__ void k_trans5(const float* __restrict__ w1, const float* __restrict__ w2,
                         const float* __restrict__ uw1, const float* __restrict__ uw2,
                         short* __restrict__ w1aT, short* __restrict__ w1bT,
                         short* __restrict__ w2T, short* __restrict__ uw1T,
                         short* __restrict__ uw2T){
  const float* S; short* D;
  switch(blockIdx.z){
    case 0: S=w1;          D=w1aT; break;
    case 1: S=w1+256*256;  D=w1bT; break;
    case 2: S=w2;          D=w2T;  break;
    case 3: S=uw1;         D=uw1T; break;
    default: S=uw2;        D=uw2T; break;
  }
  __shared__ float t[32][33];
  int bx = blockIdx.x*32, by = blockIdx.y*32;
  int lx = threadIdx.x & 31, ly = threadIdx.x >> 5;
  #pragma unroll
  for(int r=0;r<4;r++){ int k = ly + r*8; t[k][lx] = S[(size_t)(by+k)*256 + bx+lx]; }
  __syncthreads();
  #pragma unroll
  for(int r=0;r<4;r++){
    int n = ly + r*8;
    D[(size_t)(bx+n)*256 + by+lx] = f2bf(t[lx][n]);
  }
}

// ---------------- ew_augT [n=256][c=96] bf16 ----------------
__global__ void k_ewaugT(const float* __restrict__ ew, const float* __restrict__ eb,
                         short* __restrict__ ewT){
  int n = blockIdx.x, c = threadIdx.x;
  float v = (c < 64) ? ew[(size_t)c*256 + n] : (c == 64 ? eb[n] : 0.f);
  ewT[(size_t)n*96 + c] = f2bf(v);
}

// ---------------- biasm accumulation (biasm pre-zeroed) ----------------
__global__ void k_biasm_acc(const float* __restrict__ nb, const float* __restrict__ w1,
                            const float* __restrict__ mb1, float* __restrict__ biasm){
  int j = threadIdx.x;
  int b = blockIdx.x;
  if (b == 16){ atomicAdd(&biasm[j], mb1[j]); return; }
  float s = 0.f;
  for(int k = b*16; k < b*16+16; k++)
    s += nb[k]*(w1[(size_t)k*256+j] + w1[(size_t)(256+k)*256+j]);
  atomicAdd(&biasm[j], s);
}

// ---------------- bf16 MFMA GEMM: C[M,Nld] = A[M,K] @ BT[N,K]^T (+bias)(+silu) ------
// A is bf16 (AF32=0) or fp32 (AF32=1, converted during LDS staging).
template<int K_REAL, int K_LDS, int AF32, int BIAS, int ACT, int OF32, int OBF16>
__global__ __launch_bounds__(256)
void k_gemm_mfma(const void* __restrict__ A, const short* __restrict__ BT,
                 const float* __restrict__ bias, float* __restrict__ Cf,
                 short* __restrict__ Cb, int M, int Nld){
  __shared__ __align__(16) short As[32][K_LDS];
  const int CHL = K_LDS/8, CH = K_REAL/8;
  int tid = threadIdx.x;
  int m0 = blockIdx.y*32, n0 = blockIdx.x*256;
  for(int c = tid; c < 32*CHL; c += 256){
    int row = c / CHL, ch = c % CHL;
    short8 v;
    if (ch < CH) {
      if (AF32){
        const float* Af = (const float*)A;
        float4 f0 = *(const float4*)&Af[(size_t)(m0+row)*K_REAL + ch*8];
        float4 f1 = *(const float4*)&Af[(size_t)(m0+row)*K_REAL + ch*8 + 4];
        v[0]=f2bf(f0.x); v[1]=f2bf(f0.y); v[2]=f2bf(f0.z); v[3]=f2bf(f0.w);
        v[4]=f2bf(f1.x); v[5]=f2bf(f1.y); v[6]=f2bf(f1.z); v[7]=f2bf(f1.w);
      } else {
        v = *(const short8*)&((const short*)A)[(size_t)(m0+row)*K_REAL + ch*8];
      }
    } else {
      v = (short8){0,0,0,0,0,0,0,0};
    }
    *(short8*)&As[row][(ch ^ (row&7))*8] = v;
  }
  __syncthreads();
  int wid = tid>>6, lane = tid&63, l15 = lane&15, lq = lane>>4;
  int ncol0 = n0 + wid*64;
  f32x4 acc[2][4];
  #pragma unroll
  for(int mt=0;mt<2;mt++)
    #pragma unroll
    for(int nt=0;nt<4;nt++) acc[mt][nt] = (f32x4){0.f,0.f,0.f,0.f};
  for(int k0=0;k0<K_REAL;k0+=32){
    int kc = k0 + 8*lq;
    short8 a[2], b[4];
    #pragma unroll
    for(int mt=0;mt<2;mt++){
      int row = mt*16 + l15;
      a[mt] = *(const short8*)&As[row][kc ^ ((row&7)<<3)];
    }
    #pragma unroll
    for(int nt=0;nt<4;nt++){
      int col = ncol0 + nt*16 + l15;
      b[nt] = *(const short8*)&BT[(size_t)col*K_REAL + kc];
    }
    #pragma unroll
    for(int mt=0;mt<2;mt++)
      #pragma unroll
      for(int nt=0;nt<4;nt++)
        acc[mt][nt] = __builtin_amdgcn_mfma_f32_16x16x32_bf16(a[mt], b[nt], acc[mt][nt], 0, 0, 0);
  }
  #pragma unroll
  for(int mt=0;mt<2;mt++){
    #pragma unroll
    for(int nt=0;nt<4;nt++){
      int col = ncol0 + nt*16 + l15;
      float bb = BIAS ? bias[col] : 0.f;
      #pragma unroll
      for(int r=0;r<4;r++){
        int row = m0 + mt*16 + lq*4 + r;
        float v = acc[mt][nt][r] + bb;
        if (ACT) v = silu_f(v);
        if (OF32)  Cf[(size_t)row*Nld + col] = v;
        if (OBF16) Cb[(size_t)row*Nld + col] = f2bf(v);
      }
    }
  }
}

// ---------------- fused edge kernel (MFMA + segmented reduce) ----------------
// Edges sorted by dst. 32 edges/block. h = silu(gather + dist*w1c + biasm) in LDS.
// out = silu(h @ w2 + b2) staged in LDS [col][edge]; per-column run scan over the
// (sorted) 32 dsts emits one atomicAdd per distinct dst.
__global__ __launch_bounds__(256)
void k_edge_mfma(const short* __restrict__ t_ab,
                 const float* __restrict__ dist_s,
                 const int* __restrict__ src_s, const int* __restrict__ dst_s,
                 const float* __restrict__ w1c, const float* __restrict__ biasm,
                 const short* __restrict__ w2T, const float* __restrict__ b2,
                 float* __restrict__ aggr)
{
  // union: h [32][256] bf16 (16KB) | outl [256][33] f32 (33KB)
  __shared__ __align__(16) unsigned char ulds[256*33*4];
  short (*h)[256] = (short(*)[256])ulds;
  float* outl = (float*)ulds;
  __shared__ int sdst[32], ssrc[32];
  __shared__ float sdist[32];
  int tid = threadIdx.x;
  int e0 = blockIdx.x*32;
  if (tid < 32){
    sdst[tid] = dst_s[e0 + tid];
    ssrc[tid] = src_s[e0 + tid];
    sdist[tid] = dist_s[e0 + tid];
  }
  __syncthreads();
  int wid = tid>>6, lane = tid&63;
  int half = lane>>5, cl = lane&31;          // 16B chunk: cols 8cl..8cl+7
  float wc8[8], bm8[8];
  {
    float4 w0 = *(const float4*)&w1c[8*cl], w1v = *(const float4*)&w1c[8*cl+4];
    float4 b0 = *(const float4*)&biasm[8*cl], b1v = *(const float4*)&biasm[8*cl+4];
    wc8[0]=w0.x; wc8[1]=w0.y; wc8[2]=w0.z; wc8[3]=w0.w;
    wc8[4]=w1v.x; wc8[5]=w1v.y; wc8[6]=w1v.z; wc8[7]=w1v.w;
    bm8[0]=b0.x; bm8[1]=b0.y; bm8[2]=b0.z; bm8[3]=b0.w;
    bm8[4]=b1v.x; bm8[5]=b1v.y; bm8[6]=b1v.z; bm8[7]=b1v.w;
  }
  #pragma unroll
  for(int p=0;p<4;p++){
    int e = wid*8 + p*2 + half;
    int d = sdst[e], s = ssrc[e];
    float de = sdist[e];
    short8 va = *(const short8*)&t_ab[(size_t)d*512 + 8*cl];
    short8 vb = *(const short8*)&t_ab[(size_t)s*512 + 256 + 8*cl];
    short8 hv;
    #pragma unroll
    for(int i=0;i<8;i++){
      float f = bf2f(va[i]) + bf2f(vb[i]) + de*wc8[i] + bm8[i];
      hv[i] = f2bf(silu_f(f));
    }
    *(short8*)&h[e][(8*cl) ^ ((e&7)<<3)] = hv;
  }
  __syncthreads();

  int l15 = lane & 15, lq = lane >> 4;
  int nb = wid*64;
  f32x4 acc[2][4];
  #pragma unroll
  for(int mt=0;mt<2;mt++)
    #pragma unroll
    for(int nt=0;nt<4;nt++) acc[mt][nt] = (f32x4){0.f,0.f,0.f,0.f};

  for(int k0=0;k0<256;k0+=32){
    int kc = k0 + 8*lq;
    short8 a[2], b[4];
    #pragma unroll
    for(int mt=0;mt<2;mt++){
      int row = mt*16 + l15;
      a[mt] = *(const short8*)&h[row][kc ^ ((row&7)<<3)];
    }
    #pragma unroll
    for(int nt=0;nt<4;nt++){
      int col = nb + nt*16 + l15;
      b[nt] = *(const short8*)&w2T[(size_t)col*256 + kc];
    }
    #pragma unroll
    for(int mt=0;mt<2;mt++)
      #pragma unroll
      for(int nt=0;nt<4;nt++)
        acc[mt][nt] = __builtin_amdgcn_mfma_f32_16x16x32_bf16(a[mt], b[nt], acc[mt][nt], 0, 0, 0);
  }
  __syncthreads();   // all h reads complete before outl overwrites the union

  #pragma unroll
  for(int mt=0;mt<2;mt++){
    #pragma unroll
    for(int nt=0;nt<4;nt++){
      int col = nb + nt*16 + l15;
      float bb = b2[col];
      #pragma unroll
      for(int r=0;r<4;r++){
        int row = mt*16 + lq*4 + r;
        outl[col*33 + row] = silu_f(acc[mt][nt][r] + bb);
      }
    }
  }
  __syncthreads();

  // segmented scan: column j = tid, runs of equal dst (wave-uniform branches)
  int j = tid;
  float accu = 0.f;
  int prev = sdst[0];
  #pragma unroll
  for(int e=0;e<32;e++){
    int d = sdst[e];
    if (d != prev){
      atomicAdd(&aggr[(size_t)prev*256 + j], accu);
      accu = 0.f; prev = d;
    }
    accu += outl[j*33 + e];
  }
  atomicAdd(&aggr[(size_t)prev*256 + j], accu);
}

// ---------------- batch-segmented pooling ----------------
__global__ void k_ghist(const int* __restrict__ batch, int* __restrict__ gcnt){
  int n = blockIdx.x*256 + threadIdx.x;
  if (n >= N_NODES) return;
  atomicAdd(&gcnt[batch[n]], 1);
}
__global__ void k_gscan(const int* __restrict__ gcnt, int* __restrict__ gptr){
  if (threadIdx.x == 0){
    int s = 0;
    for(int g=0; g<NGRAPH; g++){ gptr[g]=s; s += gcnt[g]; }
    gptr[NGRAPH] = s;
  }
}
__global__ void k_pool_seg(const float* __restrict__ x, const int* __restrict__ gptr,
                           float* __restrict__ pooled){
  int g = blockIdx.x, j = threadIdx.x;
  int b = gptr[g], e = gptr[g+1];
  float s = 0.f;
  for(int n=b; n<e; n++) s += x[(size_t)n*256 + j];
  pooled[g*256 + j] = s;
}

// ---------------- head ----------------
__global__ void k_head(const float* __restrict__ pooled, const float* __restrict__ fw1,
                       const float* __restrict__ fb1, const float* __restrict__ fw2,
                       const float* __restrict__ fb2, float* __restrict__ out){
  __shared__ float red[256];
  int g = blockIdx.x, j = threadIdx.x;
  float s = fb1[j];
  const float* p = &pooled[g*256];
  for(int k=0;k<256;k++) s += p[k]*fw1[k*256+j];
  float hv = silu_f(s)*fw2[j];
  red[j]=hv; __syncthreads();
  for(int off=128;off>0;off>>=1){ if(j<off) red[j]+=red[j+off]; __syncthreads(); }
  if(j==0) out[g] = red[0] + fb2[0];
}

extern "C" void kernel_launch(void* const* d_in, const int* in_sizes, int n_in,
                              void* d_out, int out_size, void* d_ws, size_t ws_size,
                              hipStream_t stream) {
  const float* x_in      = (const float*)d_in[0];
  const float* edge_attr = (const float*)d_in[1];
  const float* pos       = (const float*)d_in[2];
  const int*   ei        = (const int*)d_in[3];
  const int*   batch     = (const int*)d_in[4];
  const float* node_w    = (const float*)d_in[5];
  const float* node_b    = (const float*)d_in[6];
  const float* edge_w    = (const float*)d_in[7];
  const float* edge_b    = (const float*)d_in[8];
  const float* msg_w1    = (const float*)d_in[9];
  const float* msg_b1    = (const float*)d_in[10];
  const float* msg_w2    = (const float*)d_in[11];
  const float* msg_b2    = (const float*)d_in[12];
  const float* upd_w1    = (const float*)d_in[13];
  const float* upd_b1    = (const float*)d_in[14];
  const float* upd_w2    = (const float*)d_in[15];
  const float* upd_b2    = (const float*)d_in[16];
  const float* fc_w1     = (const float*)d_in[17];
  const float* fc_b1     = (const float*)d_in[18];
  const float* fc_w2     = (const float*)d_in[19];
  const float* fc_b2     = (const float*)d_in[20];
  float* out = (float*)d_out;

  float* ws = (float*)d_ws;
  // CSR / sort
  int* cnt     = (int*)ws; ws += N_NODES;
  int* off     = (int*)ws; ws += N_NODES;
  int* row_ptr = (int*)ws; ws += N_NODES+4;
  int* src_s   = (int*)ws; ws += N_EDGES;
  int* dst_s   = (int*)ws; ws += N_EDGES;
  int* eid_s   = (int*)ws; ws += N_EDGES;
  float* dist_s= ws; ws += N_EDGES;
  int* gcnt    = (int*)ws; ws += NGRAPH;
  int* gptr    = (int*)ws; ws += NGRAPH+4;
  // data
  short* x_bf   = (short*)ws; ws += (size_t)N_NODES*256/2;
  float* EA_aug = ws; ws += (size_t)N_NODES*96;
  short* WabT   = (short*)ws; ws += 512*256/2;
  short* w1aT   = (short*)ws; ws += 256*256/2;
  short* w1bT   = (short*)ws; ws += 256*256/2;
  short* w2T    = (short*)ws; ws += 256*256/2;
  short* uw1T   = (short*)ws; ws += 256*256/2;
  short* uw2T   = (short*)ws; ws += 256*256/2;
  short* ewT    = (short*)ws; ws += 256*96/2;
  short* nw_bf  = (short*)ws; ws += 256*256/2;
  float* biasm  = ws; ws += 256;
  float* tabreg = ws; ws += (size_t)N_NODES*256;   // t_ab bf16 [N][512] / h_bf
  float* aggr   = ws; ws += (size_t)N_NODES*256;
  float* pooled = ws; ws += NGRAPH*256;

  short* t_ab   = (short*)tabreg;
  short* h_bf   = (short*)tabreg;                  // alias: t_ab dead after edge kernel
  float* xfinal = aggr;                            // alias: aggr dead after upd1

  // ---- one-time per call: CSR sort, distances, EA aggregation, batch ptrs ----
  hipMemsetAsync(cnt, 0, N_NODES*sizeof(int), stream);
  k_hist<<<(N_EDGES+255)/256, 256, 0, stream>>>(ei, cnt);
  k_scan<<<1, 256, 0, stream>>>(cnt, row_ptr, off);
  k_scatter<<<(N_EDGES+255)/256, 256, 0, stream>>>(ei, off, src_s, dst_s, eid_s);
  k_dist_s<<<(N_EDGES+255)/256, 256, 0, stream>>>(src_s, dst_s, pos, dist_s);
  k_eaagg_s<<<N_NODES/4, 256, 0, stream>>>(row_ptr, eid_s, edge_attr, EA_aug);
  hipMemsetAsync(gcnt, 0, NGRAPH*sizeof(int), stream);
  k_ghist<<<(N_NODES+255)/256, 256, 0, stream>>>(batch, gcnt);
  k_gscan<<<1, 64, 0, stream>>>(gcnt, gptr);

  for(int l=0;l<4;l++){
    const float* nw  = node_w + (size_t)l*256*256;
    const float* nb  = node_b + l*256;
    const float* w1  = msg_w1 + (size_t)l*513*256;
    const float* mb1 = msg_b1 + l*256;
    const float* w2  = msg_w2 + (size_t)l*256*256;
    const float* mb2 = msg_b2 + l*256;
    const float* ewp = edge_w + (size_t)l*64*256;
    const float* ebp = edge_b + l*256;
    const float* uw1 = upd_w1 + (size_t)l*256*256;
    const float* ub1 = upd_b1 + l*256;
    const float* uw2 = upd_w2 + (size_t)l*256*256;
    const float* ub2 = upd_b2 + l*256;

    // weight prep
    k_trans5<<<dim3(8,8,5), 256, 0, stream>>>(w1, w2, uw1, uw2, w1aT, w1bT, w2T, uw1T, uw2T);
    k_ewaugT<<<256, 96, 0, stream>>>(ewp, ebp, ewT);
    k_f2b<<<64, 256, 0, stream>>>(nw, nw_bf, 256*256/4);
    // WabT[n][k] = (nw @ w1a)^T : A=w1aT, BT=nw_bf
    k_gemm_mfma<256,256,0,0,0,0,1><<<dim3(1,8), 256, 0, stream>>>(w1aT, nw_bf, nullptr, nullptr, WabT,         256, 256);
    k_gemm_mfma<256,256,0,0,0,0,1><<<dim3(1,8), 256, 0, stream>>>(w1bT, nw_bf, nullptr, nullptr, WabT+256*256, 256, 256);
    hipMemsetAsync(biasm, 0, 256*sizeof(float), stream);
    k_biasm_acc<<<17, 256, 0, stream>>>(nb, w1, mb1, biasm);

    // t_ab[N][512] = x @ [Wa|Wb]   (layer 0 reads fp32 x_in directly)
    if (l == 0)
      k_gemm_mfma<256,256,1,0,0,0,1><<<dim3(2,625), 256, 0, stream>>>(x_in, WabT, nullptr, nullptr, t_ab, N_NODES, 512);
    else
      k_gemm_mfma<256,256,0,0,0,0,1><<<dim3(2,625), 256, 0, stream>>>(x_bf, WabT, nullptr, nullptr, t_ab, N_NODES, 512);

    // aggr = EA_aug @ ew_augT (folded edge-embedding segment-sum), fp32 A staged
    k_gemm_mfma<96,128,1,0,0,1,0><<<dim3(1,625), 256, 0, stream>>>(EA_aug, ewT, nullptr, aggr, nullptr, N_NODES, 256);

    k_edge_mfma<<<N_EDGES/32, 256, 0, stream>>>(t_ab, dist_s, src_s, dst_s,
                                                w1 + 512*256, biasm, w2T, mb2, aggr);

    // update MLP (upd1 reads fp32 aggr directly)
    k_gemm_mfma<256,256,1,1,1,0,1><<<dim3(1,625), 256, 0, stream>>>(aggr, uw1T, ub1, nullptr, h_bf, N_NODES, 256);
    if (l < 3)
      k_gemm_mfma<256,256,0,1,0,0,1><<<dim3(1,625), 256, 0, stream>>>(h_bf, uw2T, ub2, nullptr, x_bf, N_NODES, 256);
    else
      k_gemm_mfma<256,256,0,1,0,1,0><<<dim3(1,625), 256, 0, stream>>>(h_bf, uw2T, ub2, xfinal, nullptr, N_NODES, 256);
  }

  k_pool_seg<<<NGRAPH, 256, 0, stream>>>(xfinal, gptr, pooled);
  k_head<<<NGRAPH, 256, 0, stream>>>(pooled, fc_w1, fc_b1, fc_w2, fc_b2, out);
}